// Round 5
// baseline (585.072 us; speedup 1.0000x reference)
//
#include <hip/hip_runtime.h>
#include <hip/hip_cooperative_groups.h>
#include <math.h>

namespace cg = cooperative_groups;

#define NTYPE   4
#define NWAVE   8
#define NORBIT  128
#define NEIGH   64
#define NB      32
#define NATOM   256
#define NPP     (NATOM * NEIGH)   /* 16384 pairs per batch */
#define NPAIR   (NB * NPP)        /* 524288 */
#define TOTATOM (NB * NATOM)      /* 8192  */
#define NPARA   13                /* 1 + 3 + 9 */
#define CAP     128               /* rec slots per atom (mean 64) */

__device__ __forceinline__ float fast_tanh(float x) {
    float ax = fabsf(x);
    float e  = __expf(-2.0f * ax);
    float r  = (1.0f - e) / (1.0f + e);
    return copysignf(r, x);
}

// ---- phase 0: zero cnt, coeff0[a][w] = params[species[a]][w] ---------------
__device__ __forceinline__ void setup_range(int g0, int stride,
                                            const int* __restrict__ species,
                                            const float* __restrict__ params,
                                            float* __restrict__ coeff0,
                                            int* __restrict__ cnt) {
    for (int g = g0; g < TOTATOM; g += stride) {
        cnt[g] = 0;
        int sp = species[g];
#pragma unroll
        for (int w = 0; w < NWAVE; w++) coeff0[g * NWAVE + w] = params[sp * NWAVE + w];
    }
}

// ---- phase 1: scatter pairs into rec[atom][CAP] ----------------------------
__device__ __forceinline__ void scatter_range(int p0, int stride,
                                              const int* __restrict__ atom_index,
                                              const float* __restrict__ cart,
                                              const float* __restrict__ shifts,
                                              const int* __restrict__ species,
                                              int* __restrict__ cnt,
                                              float4* __restrict__ rec) {
    for (int p = p0; p < NPAIR; p += stride) {
        int b = p >> 14;                       // NPP = 2^14
        int i = atom_index[p];
        int j = atom_index[NPAIR + p];
        int ig = b * NATOM + i;
        int jg = b * NATOM + j;
        float dx = cart[ig * 3 + 0] - cart[jg * 3 + 0] + shifts[p * 3 + 0];
        float dy = cart[ig * 3 + 1] - cart[jg * 3 + 1] + shifts[p * 3 + 1];
        float dz = cart[ig * 3 + 2] - cart[jg * 3 + 2] + shifts[p * 3 + 2];
        int sp = species[jg];
        int pos = atomicAdd(&cnt[ig], 1);
        if (pos < CAP)
            rec[(size_t)ig * CAP + pos] =
                make_float4(dx, dy, dz, __int_as_float(jg | (sp << 16)));
    }
}

// ---- one density pass for one atom (one wave); syncs are unconditional -----
__device__ __forceinline__ void density_pass(
    int a, bool active, int lane, int pl, int w,
    const float4* __restrict__ rec, const int* __restrict__ cnt,
    const float* __restrict__ coeff_in,
    float rs0, float rs1, float rs2, float rs3,
    float in0, float in1, float in2, float in3,
    const float* __restrict__ hyper,
    const float* __restrict__ W, const float* __restrict__ E,
    const int* __restrict__ species,
    float* __restrict__ coeff_out, float* __restrict__ density_out,
    float* lds, int mode)
{
    int n = 0;
    if (active) { n = cnt[a]; if (n > CAP) n = CAP; }
    const float4* ra = rec + (size_t)a * CAP;

    float S[NPARA];
#pragma unroll
    for (int k = 0; k < NPARA; k++) S[k] = 0.0f;

    int idx = pl;
    float4 r = active ? ra[idx] : make_float4(0.f, 0.f, 0.f, 0.f);
    while (idx < n) {
        float4 rn = ra[idx + 8];              // prefetch (stays within ws)
        int jp = __float_as_int(r.w);
        int j  = jp & 0xFFFF;
        int sp = jp >> 16;
        float cj = coeff_in[j * NWAVE + w];
        float d2 = r.x * r.x + r.y * r.y + r.z * r.z;
        float d  = sqrtf(d2);
        float c  = __cosf(d * 0.62831853071795864769f);   // pi / CUTOFF
        float fc = 0.5f * c + 0.5f;
        fc = fc * fc;
        float rw = (sp == 0) ? rs0 : (sp == 1) ? rs1 : (sp == 2) ? rs2 : rs3;
        float iw = (sp == 0) ? in0 : (sp == 1) ? in1 : (sp == 2) ? in2 : in3;
        float dr  = d - rw;
        float rad = __expf(iw * dr * dr);
        float q = fc * rad * cj;
        S[0] += q;
        float qx = q * r.x, qy = q * r.y, qz = q * r.z;
        S[1] += qx; S[2] += qy; S[3] += qz;
        S[4]  += qx * r.x; S[5]  += qx * r.y; S[6]  += qx * r.z;
        S[7]  += qy * r.x; S[8]  += qy * r.y; S[9]  += qy * r.z;
        S[10] += qz * r.x; S[11] += qz * r.y; S[12] += qz * r.z;
        idx += 8;
        r = rn;
    }

    // reduce over 8 pair sub-lanes (bits 3..5 of lane)
#pragma unroll
    for (int k = 0; k < NPARA; k++) {
        S[k] += __shfl_xor(S[k], 8, 64);
        S[k] += __shfl_xor(S[k], 16, 64);
        S[k] += __shfl_xor(S[k], 32, 64);
    }

    __syncthreads();                          // protect lds from previous pass
    if (pl == 0) {
#pragma unroll
        for (int k = 0; k < NPARA; k++) lds[w * 16 + k] = S[k];
    }
    __syncthreads();

    // projection: hyper read once per (w,ip); hw accumulators in regs
    const int o0 = lane, o1 = lane + 64;
    float hw0[NPARA], hw1[NPARA];
#pragma unroll
    for (int k = 0; k < NPARA; k++) { hw0[k] = 0.0f; hw1[k] = 0.0f; }
#pragma unroll
    for (int w2 = 0; w2 < NWAVE; w2++) {
        const float* Sw = lds + w2 * 16;
        float4 s0 = *(const float4*)(Sw);
        float4 s1 = *(const float4*)(Sw + 4);
        float4 s2 = *(const float4*)(Sw + 8);
        float  sc = Sw[12];
        float h00 = hyper[w2 * NORBIT + o0];
        float h01 = hyper[w2 * NORBIT + o1];
        float h10 = hyper[(NWAVE + w2) * NORBIT + o0];
        float h11 = hyper[(NWAVE + w2) * NORBIT + o1];
        float h20 = hyper[(2 * NWAVE + w2) * NORBIT + o0];
        float h21 = hyper[(2 * NWAVE + w2) * NORBIT + o1];
        hw0[0]  += s0.x * h00; hw1[0]  += s0.x * h01;
        hw0[1]  += s0.y * h10; hw1[1]  += s0.y * h11;
        hw0[2]  += s0.z * h10; hw1[2]  += s0.z * h11;
        hw0[3]  += s0.w * h10; hw1[3]  += s0.w * h11;
        hw0[4]  += s1.x * h20; hw1[4]  += s1.x * h21;
        hw0[5]  += s1.y * h20; hw1[5]  += s1.y * h21;
        hw0[6]  += s1.z * h20; hw1[6]  += s1.z * h21;
        hw0[7]  += s1.w * h20; hw1[7]  += s1.w * h21;
        hw0[8]  += s2.x * h20; hw1[8]  += s2.x * h21;
        hw0[9]  += s2.y * h20; hw1[9]  += s2.y * h21;
        hw0[10] += s2.z * h20; hw1[10] += s2.z * h21;
        hw0[11] += s2.w * h20; hw1[11] += s2.w * h21;
        hw0[12] += sc   * h20; hw1[12] += sc   * h21;
    }
    float acc0 = 0.0f, acc1 = 0.0f;
#pragma unroll
    for (int k = 0; k < NPARA; k++) {
        acc0 += hw0[k] * hw0[k];
        acc1 += hw1[k] * hw1[k];
    }

    if (mode == 1) {
        if (active) {
            density_out[a * NORBIT + o0] = acc0;
            density_out[a * NORBIT + o1] = acc1;
        }
        return;
    }

    // fused coeff update: part[w2] = sum_o density[o] * W[o][w2]
    float part[NWAVE];
#pragma unroll
    for (int w2 = 0; w2 < NWAVE; w2++)
        part[w2] = acc0 * W[o0 * NWAVE + w2] + acc1 * W[o1 * NWAVE + w2];
#pragma unroll
    for (int mask = 1; mask < 64; mask <<= 1) {
#pragma unroll
        for (int w2 = 0; w2 < NWAVE; w2++)
            part[w2] += __shfl_xor(part[w2], mask, 64);
    }
    if (active && lane < NWAVE) {
        int sp = species[a];
        coeff_out[a * NWAVE + lane] =
            coeff_in[a * NWAVE + lane] + fast_tanh(part[lane] + E[sp * NWAVE + lane]);
    }
}

// ================= cooperative fused kernel (grid-size-agnostic) ============
__global__ __launch_bounds__(256, 4) void k_fused(
    const int* __restrict__ atom_index, const float* __restrict__ cart,
    const float* __restrict__ shifts, const int* __restrict__ species,
    const float* __restrict__ params, const float* __restrict__ rs,
    const float* __restrict__ inta, const float* __restrict__ hyper,
    const float* __restrict__ W0, const float* __restrict__ E0,
    const float* __restrict__ W1, const float* __restrict__ E1,
    float* __restrict__ coeffA, float* __restrict__ coeffB,
    int* __restrict__ cnt, float4* __restrict__ rec, float* __restrict__ out)
{
    cg::grid_group grid = cg::this_grid();
    const int bl = blockIdx.x, t = threadIdx.x, G = gridDim.x;
    const int lane = t & 63, wv = t >> 6;
    const int pl = lane >> 3, w = lane & 7;
    __shared__ float lds_S[4][NWAVE * 16];

    float rs0 = rs[w],   rs1 = rs[8 + w],   rs2 = rs[16 + w],   rs3 = rs[24 + w];
    float in0 = inta[w], in1 = inta[8 + w], in2 = inta[16 + w], in3 = inta[24 + w];

    setup_range(bl * 256 + t, G * 256, species, params, coeffA, cnt);
    __threadfence();
    grid.sync();

    scatter_range(bl * 256 + t, G * 256, atom_index, cart, shifts, species, cnt, rec);
    __threadfence();
    grid.sync();

    const int slots = G * 4;                       // wave-slots per sweep
    const int iters = (TOTATOM + slots - 1) / slots;

#pragma unroll 1
    for (int ii = 0; ii < iters; ii++) {
        int a = ii * slots + bl * 4 + wv;
        density_pass(a, a < TOTATOM, lane, pl, w, rec, cnt, coeffA,
                     rs0, rs1, rs2, rs3, in0, in1, in2, in3,
                     hyper, W0, E0, species, coeffB, out, lds_S[wv], 0);
    }
    __threadfence();
    grid.sync();

#pragma unroll 1
    for (int ii = 0; ii < iters; ii++) {
        int a = ii * slots + bl * 4 + wv;
        density_pass(a, a < TOTATOM, lane, pl, w, rec, cnt, coeffB,
                     rs0, rs1, rs2, rs3, in0, in1, in2, in3,
                     hyper, W1, E1, species, coeffA, out, lds_S[wv], 0);
    }
    __threadfence();
    grid.sync();

#pragma unroll 1
    for (int ii = 0; ii < iters; ii++) {
        int a = ii * slots + bl * 4 + wv;
        density_pass(a, a < TOTATOM, lane, pl, w, rec, cnt, coeffA,
                     rs0, rs1, rs2, rs3, in0, in1, in2, in3,
                     hyper, W1, E1, species, coeffB, out, lds_S[wv], 1);
    }
}

// ================= fallback multi-kernel path ===============================
__global__ __launch_bounds__(256) void k_setup(const int* __restrict__ species,
                                               const float* __restrict__ params,
                                               float* __restrict__ coeff0,
                                               int* __restrict__ cnt) {
    setup_range(blockIdx.x * 256 + threadIdx.x, gridDim.x * 256, species, params, coeff0, cnt);
}

__global__ __launch_bounds__(256) void k_scatter(const int* __restrict__ atom_index,
                                                 const float* __restrict__ cart,
                                                 const float* __restrict__ shifts,
                                                 const int* __restrict__ species,
                                                 int* __restrict__ cnt,
                                                 float4* __restrict__ rec) {
    scatter_range(blockIdx.x * 256 + threadIdx.x, gridDim.x * 256,
                  atom_index, cart, shifts, species, cnt, rec);
}

__global__ __launch_bounds__(256) void k_pass(const float4* __restrict__ rec,
                                              const int* __restrict__ cnt,
                                              const float* __restrict__ coeff_in,
                                              const float* __restrict__ rs,
                                              const float* __restrict__ inta,
                                              const float* __restrict__ hyper,
                                              const float* __restrict__ W,
                                              const float* __restrict__ E,
                                              const int* __restrict__ species,
                                              float* __restrict__ coeff_out,
                                              float* __restrict__ density_out,
                                              int mode) {
    const int t = threadIdx.x;
    const int lane = t & 63, wv = t >> 6;
    const int pl = lane >> 3, w = lane & 7;
    __shared__ float lds_S[4][NWAVE * 16];
    float rs0 = rs[w],   rs1 = rs[8 + w],   rs2 = rs[16 + w],   rs3 = rs[24 + w];
    float in0 = inta[w], in1 = inta[8 + w], in2 = inta[16 + w], in3 = inta[24 + w];
    int a = blockIdx.x * 4 + wv;
    density_pass(a, true, lane, pl, w, rec, cnt, coeff_in,
                 rs0, rs1, rs2, rs3, in0, in1, in2, in3,
                 hyper, W, E, species, coeff_out, density_out, lds_S[wv], mode);
}

extern "C" void kernel_launch(void* const* d_in, const int* in_sizes, int n_in,
                              void* d_out, int out_size, void* d_ws, size_t ws_size,
                              hipStream_t stream) {
    const float* cart    = (const float*)d_in[0];
    const float* shifts  = (const float*)d_in[1];
    const float* rs      = (const float*)d_in[2];
    const float* inta    = (const float*)d_in[3];
    const float* params  = (const float*)d_in[4];
    const float* hyper   = (const float*)d_in[5];
    const float* w0      = (const float*)d_in[6];
    const float* e0      = (const float*)d_in[7];
    const float* w1      = (const float*)d_in[8];
    const float* e1      = (const float*)d_in[9];
    // d_in[10] = numatoms (unused, always NATOM)
    const int* species    = (const int*)d_in[11];
    const int* atom_index = (const int*)d_in[12];
    float* out = (float*)d_out;

    char* ws = (char*)d_ws;
    float4* rec   = (float4*)ws;  ws += (size_t)TOTATOM * CAP * 16;     // 16 MiB
    float* coeffA = (float*)ws;   ws += (size_t)TOTATOM * NWAVE * 4;
    float* coeffB = (float*)ws;   ws += (size_t)TOTATOM * NWAVE * 4;
    int* cnt      = (int*)ws;     ws += TOTATOM * 4;

    int occ = 0;
    hipError_t qe = hipOccupancyMaxActiveBlocksPerMultiprocessor(
        &occ, (const void*)k_fused, 256, 0);
    int grid = 512;
    if (qe == hipSuccess && occ > 0) {
        grid = occ * 256;                       // 256 CUs
        if (grid > 1024) grid = 1024;
    }

    void* kargs[] = {
        (void*)&atom_index, (void*)&cart, (void*)&shifts, (void*)&species,
        (void*)&params, (void*)&rs, (void*)&inta, (void*)&hyper,
        (void*)&w0, (void*)&e0, (void*)&w1, (void*)&e1,
        (void*)&coeffA, (void*)&coeffB, (void*)&cnt, (void*)&rec, (void*)&out
    };
    hipError_t e = hipLaunchCooperativeKernel((const void*)k_fused, dim3(grid),
                                              dim3(256), kargs, 0, stream);
    if (e != hipSuccess) {
        (void)hipGetLastError();                // clear, take fallback path
        k_setup<<<32, 256, 0, stream>>>(species, params, coeffA, cnt);
        k_scatter<<<512, 256, 0, stream>>>(atom_index, cart, shifts, species, cnt, rec);
        k_pass<<<TOTATOM / 4, 256, 0, stream>>>(rec, cnt, coeffA, rs, inta, hyper,
                                                w0, e0, species, coeffB, out, 0);
        k_pass<<<TOTATOM / 4, 256, 0, stream>>>(rec, cnt, coeffB, rs, inta, hyper,
                                                w1, e1, species, coeffA, out, 0);
        k_pass<<<TOTATOM / 4, 256, 0, stream>>>(rec, cnt, coeffA, rs, inta, hyper,
                                                w1, e1, species, coeffB, out, 1);
    }
}

// Round 6
// 165.073 us; speedup vs baseline: 3.5443x; 3.5443x over previous
//
#include <hip/hip_runtime.h>
#include <math.h>

#define NTYPE   4
#define NWAVE   8
#define NORBIT  128
#define NEIGH   64
#define NB      32
#define NATOM   256
#define NPP     (NATOM * NEIGH)   /* 16384 pairs per batch */
#define NPAIR   (NB * NPP)        /* 524288 */
#define TOTATOM (NB * NATOM)      /* 8192  */
#define NPARA   13                /* 1 + 3 + 9 */
#define CAP     128               /* rec slots per atom (mean 64) */

__device__ __forceinline__ float fast_tanh(float x) {
    float ax = fabsf(x);
    float e  = __expf(-2.0f * ax);
    float r  = (1.0f - e) / (1.0f + e);
    return copysignf(r, x);
}

// ---- scatter + precompute fc*radial; also init coeffA ----------------------
// 1024 blocks: 32 per batch, 512 pairs each. cart/species cached in LDS.
__global__ __launch_bounds__(256) void k_scatter(
    const int* __restrict__ atom_index, const float* __restrict__ cart,
    const float* __restrict__ shifts, const int* __restrict__ species,
    const float* __restrict__ params, const float* __restrict__ rs,
    const float* __restrict__ inta,
    int* __restrict__ cnt, float4* __restrict__ rec,
    float4* __restrict__ radfc, float* __restrict__ coeffA)
{
    const int bl = blockIdx.x, t = threadIdx.x;
    const int b = bl >> 5, c = bl & 31;
    __shared__ float cx[NATOM], cy[NATOM], cz[NATOM];
    __shared__ int   spl[NATOM];
    __shared__ float lrs[NTYPE * NWAVE], lin[NTYPE * NWAVE];
    if (t < NTYPE * NWAVE) { lrs[t] = rs[t]; lin[t] = inta[t]; }
    const int ag = b * NATOM + t;
    cx[t] = cart[ag * 3 + 0];
    cy[t] = cart[ag * 3 + 1];
    cz[t] = cart[ag * 3 + 2];
    spl[t] = species[ag];
    __syncthreads();

    if (c == 0) {                           // coeff init: one block per batch
        int sp = spl[t];
#pragma unroll
        for (int w = 0; w < NWAVE; w++) coeffA[ag * NWAVE + w] = params[sp * NWAVE + w];
    }

    const int base = b * NPP + c * 512;
#pragma unroll
    for (int k = 0; k < 2; k++) {
        int p = base + t + k * 256;
        int i = atom_index[p];
        int j = atom_index[NPAIR + p];
        float dx = cx[i] - cx[j] + shifts[p * 3 + 0];
        float dy = cy[i] - cy[j] + shifts[p * 3 + 1];
        float dz = cz[i] - cz[j] + shifts[p * 3 + 2];
        int sp = spl[j];
        float d  = sqrtf(dx * dx + dy * dy + dz * dz);
        float co = __cosf(d * 0.62831853071795864769f);   // pi / CUTOFF
        float fc = 0.5f * co + 0.5f;
        fc = fc * fc;
        int ig = b * NATOM + i;
        int pos = atomicAdd(&cnt[ig], 1);
        if (pos < CAP) {
            size_t s = (size_t)ig * CAP + pos;
            rec[s] = make_float4(dx, dy, dz, __int_as_float(b * NATOM + j));
            float f[NWAVE];
#pragma unroll
            for (int w = 0; w < NWAVE; w++) {
                float dr = d - lrs[sp * NWAVE + w];
                f[w] = fc * __expf(lin[sp * NWAVE + w] * dr * dr);
            }
            radfc[s * 2 + 0] = make_float4(f[0], f[1], f[2], f[3]);
            radfc[s * 2 + 1] = make_float4(f[4], f[5], f[6], f[7]);
        }
    }
}

// ---- density pass: one atom per wave; transcendental-free inner loop -------
// mode 0: coeff_out = coeff_in + tanh(density @ W + E[species])
// mode 1: write density to density_out
__global__ __launch_bounds__(256) void k_pass(
    const float4* __restrict__ rec, const float* __restrict__ radfc,
    const int* __restrict__ cnt, const float* __restrict__ coeff_in,
    const float* __restrict__ hyper, const float* __restrict__ W,
    const float* __restrict__ E, const int* __restrict__ species,
    float* __restrict__ coeff_out, float* __restrict__ density_out, int mode)
{
    const int t = threadIdx.x;
    const int lane = t & 63, wv = t >> 6;
    const int pl = lane >> 3, w = lane & 7;
    const int a = blockIdx.x * 4 + wv;
    __shared__ float lds_S[4][NWAVE * 16];

    int n = cnt[a];
    if (n > CAP) n = CAP;
    const float4* ra = rec + (size_t)a * CAP;
    const float*  rf = radfc + (size_t)a * CAP * 8;

    float S[NPARA];
#pragma unroll
    for (int k = 0; k < NPARA; k++) S[k] = 0.0f;

    int idx = pl;
    float4 r = ra[idx];                     // capacity-safe preload
    float  f = rf[idx * 8 + w];
    while (idx < n) {
        float4 rn = ra[idx + 8];            // prefetch next (stays within ws)
        float  fn = rf[(idx + 8) * 8 + w];
        int j = __float_as_int(r.w);
        float cj = coeff_in[j * NWAVE + w];
        float q = f * cj;
        S[0] += q;
        float qx = q * r.x, qy = q * r.y, qz = q * r.z;
        S[1] += qx; S[2] += qy; S[3] += qz;
        S[4]  += qx * r.x; S[5]  += qx * r.y; S[6]  += qx * r.z;
        S[7]  += qy * r.x; S[8]  += qy * r.y; S[9]  += qy * r.z;
        S[10] += qz * r.x; S[11] += qz * r.y; S[12] += qz * r.z;
        idx += 8;
        r = rn;
        f = fn;
    }

    // reduce over 8 pair sub-lanes (bits 3..5 of lane)
#pragma unroll
    for (int k = 0; k < NPARA; k++) {
        S[k] += __shfl_xor(S[k], 8, 64);
        S[k] += __shfl_xor(S[k], 16, 64);
        S[k] += __shfl_xor(S[k], 32, 64);
    }

    if (pl == 0) {
#pragma unroll
        for (int k = 0; k < NPARA; k++) lds_S[wv][w * 16 + k] = S[k];
    }
    __syncthreads();

    // projection: hyper read once per (w,ip); hw accumulators in regs
    const int o0 = lane, o1 = lane + 64;
    float hw0[NPARA], hw1[NPARA];
#pragma unroll
    for (int k = 0; k < NPARA; k++) { hw0[k] = 0.0f; hw1[k] = 0.0f; }
#pragma unroll
    for (int w2 = 0; w2 < NWAVE; w2++) {
        const float* Sw = &lds_S[wv][w2 * 16];
        float4 s0 = *(const float4*)(Sw);
        float4 s1 = *(const float4*)(Sw + 4);
        float4 s2 = *(const float4*)(Sw + 8);
        float  sc = Sw[12];
        float h00 = hyper[w2 * NORBIT + o0];
        float h01 = hyper[w2 * NORBIT + o1];
        float h10 = hyper[(NWAVE + w2) * NORBIT + o0];
        float h11 = hyper[(NWAVE + w2) * NORBIT + o1];
        float h20 = hyper[(2 * NWAVE + w2) * NORBIT + o0];
        float h21 = hyper[(2 * NWAVE + w2) * NORBIT + o1];
        hw0[0]  += s0.x * h00; hw1[0]  += s0.x * h01;
        hw0[1]  += s0.y * h10; hw1[1]  += s0.y * h11;
        hw0[2]  += s0.z * h10; hw1[2]  += s0.z * h11;
        hw0[3]  += s0.w * h10; hw1[3]  += s0.w * h11;
        hw0[4]  += s1.x * h20; hw1[4]  += s1.x * h21;
        hw0[5]  += s1.y * h20; hw1[5]  += s1.y * h21;
        hw0[6]  += s1.z * h20; hw1[6]  += s1.z * h21;
        hw0[7]  += s1.w * h20; hw1[7]  += s1.w * h21;
        hw0[8]  += s2.x * h20; hw1[8]  += s2.x * h21;
        hw0[9]  += s2.y * h20; hw1[9]  += s2.y * h21;
        hw0[10] += s2.z * h20; hw1[10] += s2.z * h21;
        hw0[11] += s2.w * h20; hw1[11] += s2.w * h21;
        hw0[12] += sc   * h20; hw1[12] += sc   * h21;
    }
    float acc0 = 0.0f, acc1 = 0.0f;
#pragma unroll
    for (int k = 0; k < NPARA; k++) {
        acc0 += hw0[k] * hw0[k];
        acc1 += hw1[k] * hw1[k];
    }

    if (mode == 1) {
        density_out[a * NORBIT + o0] = acc0;
        density_out[a * NORBIT + o1] = acc1;
        return;
    }

    // fused coeff update: part[w2] = sum_o density[o] * W[o][w2]
    float part[NWAVE];
#pragma unroll
    for (int w2 = 0; w2 < NWAVE; w2++)
        part[w2] = acc0 * W[o0 * NWAVE + w2] + acc1 * W[o1 * NWAVE + w2];
#pragma unroll
    for (int mask = 1; mask < 64; mask <<= 1) {
#pragma unroll
        for (int w2 = 0; w2 < NWAVE; w2++)
            part[w2] += __shfl_xor(part[w2], mask, 64);
    }
    if (lane < NWAVE) {
        int sp = species[a];
        coeff_out[a * NWAVE + lane] =
            coeff_in[a * NWAVE + lane] + fast_tanh(part[lane] + E[sp * NWAVE + lane]);
    }
}

extern "C" void kernel_launch(void* const* d_in, const int* in_sizes, int n_in,
                              void* d_out, int out_size, void* d_ws, size_t ws_size,
                              hipStream_t stream) {
    const float* cart    = (const float*)d_in[0];
    const float* shifts  = (const float*)d_in[1];
    const float* rs      = (const float*)d_in[2];
    const float* inta    = (const float*)d_in[3];
    const float* params  = (const float*)d_in[4];
    const float* hyper   = (const float*)d_in[5];
    const float* w0      = (const float*)d_in[6];
    const float* e0      = (const float*)d_in[7];
    const float* w1      = (const float*)d_in[8];
    const float* e1      = (const float*)d_in[9];
    // d_in[10] = numatoms (unused, always NATOM)
    const int* species    = (const int*)d_in[11];
    const int* atom_index = (const int*)d_in[12];
    float* out = (float*)d_out;

    char* ws = (char*)d_ws;
    float4* rec   = (float4*)ws;  ws += (size_t)TOTATOM * CAP * 16;      // 16 MiB
    float4* radfc = (float4*)ws;  ws += (size_t)TOTATOM * CAP * 32;     // 32 MiB
    float* coeffA = (float*)ws;   ws += (size_t)TOTATOM * NWAVE * 4;
    float* coeffB = (float*)ws;   ws += (size_t)TOTATOM * NWAVE * 4;
    int* cnt      = (int*)ws;     ws += TOTATOM * 4;

    hipMemsetAsync(cnt, 0, TOTATOM * 4, stream);
    k_scatter<<<1024, 256, 0, stream>>>(atom_index, cart, shifts, species, params,
                                        rs, inta, cnt, rec, radfc, coeffA);
    k_pass<<<TOTATOM / 4, 256, 0, stream>>>(rec, (const float*)radfc, cnt, coeffA,
                                            hyper, w0, e0, species, coeffB, out, 0);
    k_pass<<<TOTATOM / 4, 256, 0, stream>>>(rec, (const float*)radfc, cnt, coeffB,
                                            hyper, w1, e1, species, coeffA, out, 0);
    k_pass<<<TOTATOM / 4, 256, 0, stream>>>(rec, (const float*)radfc, cnt, coeffA,
                                            hyper, w1, e1, species, coeffB, out, 1);
}